// Round 1
// baseline (99.049 us; speedup 1.0000x reference)
//
#include <hip/hip_runtime.h>
#include <hip/hip_bf16.h>

typedef __attribute__((ext_vector_type(4))) float f32x4;
typedef __attribute__((ext_vector_type(8))) short bf16x8;

#define NNODES 10000
#define KDIM 512
#define NDIM 512
#define NEDGES 160000

__device__ __forceinline__ unsigned short f2bf(float f) {
    __hip_bfloat16 h = __float2bfloat16(f);
    return *reinterpret_cast<unsigned short*>(&h);
}

// ---- fp32 -> bf16 conversion, 4 elems/thread ----
__global__ __launch_bounds__(256) void cvt_kernel(const float* __restrict__ src,
                                                  unsigned short* __restrict__ dst, int n) {
    int i = (blockIdx.x * 256 + threadIdx.x) * 4;
    if (i >= n) return;
    float4 v = *reinterpret_cast<const float4*>(src + i);
    ushort4 o;
    o.x = f2bf(v.x); o.y = f2bf(v.y); o.z = f2bf(v.z); o.w = f2bf(v.w);
    *reinterpret_cast<ushort4*>(dst + i) = o;
}

// ---- bf16 MFMA GEMM: C[M][512] = A[M][512] * B[512][512]^T ----
// 128x128 tile, BK=32, 4 waves in 2x2, each wave 64x64 (4x4 fragments of 16x16)
__global__ __launch_bounds__(256) void gemm_kernel(const unsigned short* __restrict__ A,
                                                   const unsigned short* __restrict__ B,
                                                   float* __restrict__ C, int M) {
    __shared__ unsigned short lA[128 * 32];
    __shared__ unsigned short lB[128 * 32];
    const int tid = threadIdx.x;
    const int wid = tid >> 6;
    const int lane = tid & 63;
    const int wr = wid >> 1, wc = wid & 1;
    const int m0 = blockIdx.x * 128;
    const int n0 = blockIdx.y * 128;

    f32x4 acc[4][4] = {};

    for (int k0 = 0; k0 < KDIM; k0 += 32) {
        // stage A and B tiles: 128 rows x 32 bf16 each = 8192 B; 16B/lane
        // LDS layout is linear [row][32]: li = q*256+tid, row=li>>2, seg=li&3
#pragma unroll
        for (int q = 0; q < 2; q++) {
            int li = q * 256 + tid;
            int row = li >> 2, seg = li & 3;
            int grow = m0 + row; if (grow > M - 1) grow = M - 1;  // clamp OOB rows
            const unsigned short* ga = A + (size_t)grow * KDIM + k0 + seg * 8;
            __builtin_amdgcn_global_load_lds(
                (const __attribute__((address_space(1))) void*)ga,
                (__attribute__((address_space(3))) void*)(lA + (size_t)(q * 256 + wid * 64) * 8),
                16, 0, 0);
            const unsigned short* gb = B + (size_t)(n0 + row) * KDIM + k0 + seg * 8;
            __builtin_amdgcn_global_load_lds(
                (const __attribute__((address_space(1))) void*)gb,
                (__attribute__((address_space(3))) void*)(lB + (size_t)(q * 256 + wid * 64) * 8),
                16, 0, 0);
        }
        __syncthreads();

        bf16x8 af[4], bfr[4];
#pragma unroll
        for (int i = 0; i < 4; i++)
            af[i] = *reinterpret_cast<const bf16x8*>(
                lA + (size_t)(wr * 64 + i * 16 + (lane & 15)) * 32 + (lane >> 4) * 8);
#pragma unroll
        for (int j = 0; j < 4; j++)
            bfr[j] = *reinterpret_cast<const bf16x8*>(
                lB + (size_t)(wc * 64 + j * 16 + (lane & 15)) * 32 + (lane >> 4) * 8);
#pragma unroll
        for (int i = 0; i < 4; i++)
#pragma unroll
            for (int j = 0; j < 4; j++)
                acc[i][j] = __builtin_amdgcn_mfma_f32_16x16x32_bf16(af[i], bfr[j], acc[i][j], 0, 0, 0);
        __syncthreads();
    }

    // C write: row = (lane>>4)*4 + reg, col = lane&15 within each 16x16 fragment
#pragma unroll
    for (int i = 0; i < 4; i++) {
#pragma unroll
        for (int r = 0; r < 4; r++) {
            int row = m0 + wr * 64 + i * 16 + (lane >> 4) * 4 + r;
            if (row < M) {
#pragma unroll
                for (int j = 0; j < 4; j++) {
                    int col = n0 + wc * 64 + j * 16 + (lane & 15);
                    C[(size_t)row * NDIM + col] = acc[i][j][r];
                }
            }
        }
    }
}

// ---- COO spmm (rows sorted) + bias + PReLU ----
// one block per output node; binary-search the edge range; 256 thr x float2
__global__ __launch_bounds__(256) void spmm_prelu_kernel(
    const float* __restrict__ xf,        // [NNODES][512]
    const float* __restrict__ vals,      // [E]
    const int* __restrict__ rows,        // [E] sorted
    const int* __restrict__ cols,        // [E]
    const float* __restrict__ bias,      // [512]
    const float* __restrict__ prelu_a,   // [1]
    float* __restrict__ out, int E) {
    const int node = blockIdx.x;

    // lower_bound(rows, node) and lower_bound(rows, node+1) — uniform across block
    int lo = 0, hi = E;
    while (lo < hi) { int mid = (lo + hi) >> 1; if (rows[mid] < node) lo = mid + 1; else hi = mid; }
    const int start = lo;
    hi = E;
    while (lo < hi) { int mid = (lo + hi) >> 1; if (rows[mid] < node + 1) lo = mid + 1; else hi = mid; }
    const int end = lo;

    const int t = threadIdx.x;
    float ax = 0.f, ay = 0.f;
    for (int e = start; e < end; e++) {
        float v = vals[e];
        int c = cols[e];
        float2 d = reinterpret_cast<const float2*>(xf + (size_t)c * NDIM)[t];
        ax += v * d.x;
        ay += v * d.y;
    }
    float o0 = ax + bias[2 * t];
    float o1 = ay + bias[2 * t + 1];
    float a = prelu_a[0];
    o0 = (o0 >= 0.f) ? o0 : a * o0;
    o1 = (o1 >= 0.f) ? o1 : a * o1;
    float2 r; r.x = o0; r.y = o1;
    reinterpret_cast<float2*>(out + (size_t)node * NDIM)[t] = r;
}

extern "C" void kernel_launch(void* const* d_in, const int* in_sizes, int n_in,
                              void* d_out, int out_size, void* d_ws, size_t ws_size,
                              hipStream_t stream) {
    const float* x        = (const float*)d_in[0];
    const float* fc_w     = (const float*)d_in[1];
    const float* bias     = (const float*)d_in[2];
    const float* prelu_a  = (const float*)d_in[3];
    const float* adj_vals = (const float*)d_in[4];
    const int*   adj_row  = (const int*)d_in[5];
    const int*   adj_col  = (const int*)d_in[6];
    float* out = (float*)d_out;

    char* ws = (char*)d_ws;
    unsigned short* xb = (unsigned short*)ws;                       // 10000*512*2 = 10,240,000 B
    unsigned short* wb = (unsigned short*)(ws + 10240000);          // 512*512*2   =    524,288 B
    float* xf          = (float*)(ws + 10240000 + 524288);          // 10000*512*4 = 20,480,000 B

    const int nx = NNODES * KDIM;
    const int nw = NDIM * KDIM;
    cvt_kernel<<<(nx / 4 + 255) / 256, 256, 0, stream>>>(x, xb, nx);
    cvt_kernel<<<(nw / 4 + 255) / 256, 256, 0, stream>>>(fc_w, wb, nw);

    dim3 ggrid((NNODES + 127) / 128, NDIM / 128);
    gemm_kernel<<<ggrid, 256, 0, stream>>>(xb, wb, xf, NNODES);

    spmm_prelu_kernel<<<NNODES, 256, 0, stream>>>(xf, adj_vals, adj_row, adj_col,
                                                  bias, prelu_a, out, NEDGES);
}

// Round 2
// 67.390 us; speedup vs baseline: 1.4698x; 1.4698x over previous
//
#include <hip/hip_runtime.h>
#include <hip/hip_bf16.h>

typedef __attribute__((ext_vector_type(4))) float f32x4;
typedef __attribute__((ext_vector_type(8))) short bf16x8;

#define NNODES 10000
#define KDIM 512
#define NDIM 512
#define NEDGES 160000

__device__ __forceinline__ unsigned short f2bf(float f) {
    __hip_bfloat16 h = __float2bfloat16(f);
    return *reinterpret_cast<unsigned short*>(&h);
}

// ---- fp32 -> bf16 conversion, 4 elems/thread ----
__global__ __launch_bounds__(256) void cvt_kernel(const float* __restrict__ src,
                                                  unsigned short* __restrict__ dst, int n) {
    int i = (blockIdx.x * 256 + threadIdx.x) * 4;
    if (i >= n) return;
    float4 v = *reinterpret_cast<const float4*>(src + i);
    ushort4 o;
    o.x = f2bf(v.x); o.y = f2bf(v.y); o.z = f2bf(v.z); o.w = f2bf(v.w);
    *reinterpret_cast<ushort4*>(dst + i) = o;
}

// ---- bf16 MFMA GEMM: C[M][512] = A[M][512] * B[512][512]^T, C stored as bf16 ----
// 128x128 tile, BK=32, 4 waves in 2x2, each wave 64x64 (4x4 fragments of 16x16)
__global__ __launch_bounds__(256) void gemm_kernel(const unsigned short* __restrict__ A,
                                                   const unsigned short* __restrict__ B,
                                                   unsigned short* __restrict__ C, int M) {
    __shared__ unsigned short lA[128 * 32];
    __shared__ unsigned short lB[128 * 32];
    const int tid = threadIdx.x;
    const int wid = tid >> 6;
    const int lane = tid & 63;
    const int wr = wid >> 1, wc = wid & 1;
    const int m0 = blockIdx.x * 128;
    const int n0 = blockIdx.y * 128;

    f32x4 acc[4][4] = {};

    for (int k0 = 0; k0 < KDIM; k0 += 32) {
#pragma unroll
        for (int q = 0; q < 2; q++) {
            int li = q * 256 + tid;
            int row = li >> 2, seg = li & 3;
            int grow = m0 + row; if (grow > M - 1) grow = M - 1;  // clamp OOB rows
            const unsigned short* ga = A + (size_t)grow * KDIM + k0 + seg * 8;
            __builtin_amdgcn_global_load_lds(
                (const __attribute__((address_space(1))) void*)ga,
                (__attribute__((address_space(3))) void*)(lA + (size_t)(q * 256 + wid * 64) * 8),
                16, 0, 0);
            const unsigned short* gb = B + (size_t)(n0 + row) * KDIM + k0 + seg * 8;
            __builtin_amdgcn_global_load_lds(
                (const __attribute__((address_space(1))) void*)gb,
                (__attribute__((address_space(3))) void*)(lB + (size_t)(q * 256 + wid * 64) * 8),
                16, 0, 0);
        }
        __syncthreads();

        bf16x8 af[4], bfr[4];
#pragma unroll
        for (int i = 0; i < 4; i++)
            af[i] = *reinterpret_cast<const bf16x8*>(
                lA + (size_t)(wr * 64 + i * 16 + (lane & 15)) * 32 + (lane >> 4) * 8);
#pragma unroll
        for (int j = 0; j < 4; j++)
            bfr[j] = *reinterpret_cast<const bf16x8*>(
                lB + (size_t)(wc * 64 + j * 16 + (lane & 15)) * 32 + (lane >> 4) * 8);
#pragma unroll
        for (int i = 0; i < 4; i++)
#pragma unroll
            for (int j = 0; j < 4; j++)
                acc[i][j] = __builtin_amdgcn_mfma_f32_16x16x32_bf16(af[i], bfr[j], acc[i][j], 0, 0, 0);
        __syncthreads();
    }

    // C write (bf16): row = (lane>>4)*4 + reg, col = lane&15 within each 16x16 fragment
#pragma unroll
    for (int i = 0; i < 4; i++) {
#pragma unroll
        for (int r = 0; r < 4; r++) {
            int row = m0 + wr * 64 + i * 16 + (lane >> 4) * 4 + r;
            if (row < M) {
#pragma unroll
                for (int j = 0; j < 4; j++) {
                    int col = n0 + wc * 64 + j * 16 + (lane & 15);
                    C[(size_t)row * NDIM + col] = f2bf(acc[i][j][r]);
                }
            }
        }
    }
}

// ---- COO spmm (rows sorted) + bias + PReLU, bf16 gather ----
// one WAVE per node: 64 lanes x 8 bf16 = full 512-ch row per edge (16B/lane load)
__global__ __launch_bounds__(256) void spmm_prelu_kernel(
    const unsigned short* __restrict__ xb,  // [NNODES][512] bf16
    const float* __restrict__ vals,         // [E]
    const int* __restrict__ rows,           // [E] sorted
    const int* __restrict__ cols,           // [E]
    const float* __restrict__ bias,         // [512]
    const float* __restrict__ prelu_a,      // [1]
    float* __restrict__ out, int E) {
    const int wave = threadIdx.x >> 6;
    const int lane = threadIdx.x & 63;
    const int node = blockIdx.x * 4 + wave;

    // lower_bound(rows, node) / lower_bound(rows, node+1) — wave-uniform
    int lo = 0, hi = E;
    while (lo < hi) { int mid = (lo + hi) >> 1; if (rows[mid] < node) lo = mid + 1; else hi = mid; }
    const int start = lo;
    hi = E;
    while (lo < hi) { int mid = (lo + hi) >> 1; if (rows[mid] < node + 1) lo = mid + 1; else hi = mid; }
    const int end = lo;

    float a0 = 0.f, a1 = 0.f, a2 = 0.f, a3 = 0.f, a4 = 0.f, a5 = 0.f, a6 = 0.f, a7 = 0.f;

    int e = start;
    for (; e + 1 < end; e += 2) {
        float v0 = vals[e], v1 = vals[e + 1];
        int c0 = cols[e], c1 = cols[e + 1];
        uint4 u0 = *reinterpret_cast<const uint4*>(xb + (size_t)c0 * NDIM + lane * 8);
        uint4 u1 = *reinterpret_cast<const uint4*>(xb + (size_t)c1 * NDIM + lane * 8);
        a0 += v0 * __uint_as_float(u0.x << 16);
        a1 += v0 * __uint_as_float(u0.x & 0xffff0000u);
        a2 += v0 * __uint_as_float(u0.y << 16);
        a3 += v0 * __uint_as_float(u0.y & 0xffff0000u);
        a4 += v0 * __uint_as_float(u0.z << 16);
        a5 += v0 * __uint_as_float(u0.z & 0xffff0000u);
        a6 += v0 * __uint_as_float(u0.w << 16);
        a7 += v0 * __uint_as_float(u0.w & 0xffff0000u);
        a0 += v1 * __uint_as_float(u1.x << 16);
        a1 += v1 * __uint_as_float(u1.x & 0xffff0000u);
        a2 += v1 * __uint_as_float(u1.y << 16);
        a3 += v1 * __uint_as_float(u1.y & 0xffff0000u);
        a4 += v1 * __uint_as_float(u1.z << 16);
        a5 += v1 * __uint_as_float(u1.z & 0xffff0000u);
        a6 += v1 * __uint_as_float(u1.w << 16);
        a7 += v1 * __uint_as_float(u1.w & 0xffff0000u);
    }
    if (e < end) {
        float v0 = vals[e];
        int c0 = cols[e];
        uint4 u0 = *reinterpret_cast<const uint4*>(xb + (size_t)c0 * NDIM + lane * 8);
        a0 += v0 * __uint_as_float(u0.x << 16);
        a1 += v0 * __uint_as_float(u0.x & 0xffff0000u);
        a2 += v0 * __uint_as_float(u0.y << 16);
        a3 += v0 * __uint_as_float(u0.y & 0xffff0000u);
        a4 += v0 * __uint_as_float(u0.z << 16);
        a5 += v0 * __uint_as_float(u0.z & 0xffff0000u);
        a6 += v0 * __uint_as_float(u0.w << 16);
        a7 += v0 * __uint_as_float(u0.w & 0xffff0000u);
    }

    const float4* b4 = reinterpret_cast<const float4*>(bias + lane * 8);
    float4 b0 = b4[0], b1 = b4[1];
    float al = prelu_a[0];
    float o0 = a0 + b0.x, o1 = a1 + b0.y, o2 = a2 + b0.z, o3 = a3 + b0.w;
    float o4 = a4 + b1.x, o5 = a5 + b1.y, o6 = a6 + b1.z, o7 = a7 + b1.w;
    o0 = (o0 >= 0.f) ? o0 : al * o0;
    o1 = (o1 >= 0.f) ? o1 : al * o1;
    o2 = (o2 >= 0.f) ? o2 : al * o2;
    o3 = (o3 >= 0.f) ? o3 : al * o3;
    o4 = (o4 >= 0.f) ? o4 : al * o4;
    o5 = (o5 >= 0.f) ? o5 : al * o5;
    o6 = (o6 >= 0.f) ? o6 : al * o6;
    o7 = (o7 >= 0.f) ? o7 : al * o7;
    float4 r0; r0.x = o0; r0.y = o1; r0.z = o2; r0.w = o3;
    float4 r1; r1.x = o4; r1.y = o5; r1.z = o6; r1.w = o7;
    float4* op = reinterpret_cast<float4*>(out + (size_t)node * NDIM + lane * 8);
    op[0] = r0;
    op[1] = r1;
}

extern "C" void kernel_launch(void* const* d_in, const int* in_sizes, int n_in,
                              void* d_out, int out_size, void* d_ws, size_t ws_size,
                              hipStream_t stream) {
    const float* x        = (const float*)d_in[0];
    const float* fc_w     = (const float*)d_in[1];
    const float* bias     = (const float*)d_in[2];
    const float* prelu_a  = (const float*)d_in[3];
    const float* adj_vals = (const float*)d_in[4];
    const int*   adj_row  = (const int*)d_in[5];
    const int*   adj_col  = (const int*)d_in[6];
    float* out = (float*)d_out;

    char* ws = (char*)d_ws;
    unsigned short* xb  = (unsigned short*)ws;                    // 10000*512*2 = 10,240,000 B
    unsigned short* wb  = (unsigned short*)(ws + 10240000);       // 512*512*2   =    524,288 B
    unsigned short* xfb = (unsigned short*)(ws + 10240000 + 524288); // 10000*512*2 = 10,240,000 B

    const int nx = NNODES * KDIM;
    const int nw = NDIM * KDIM;
    cvt_kernel<<<(nx / 4 + 255) / 256, 256, 0, stream>>>(x, xb, nx);
    cvt_kernel<<<(nw / 4 + 255) / 256, 256, 0, stream>>>(fc_w, wb, nw);

    dim3 ggrid((NNODES + 127) / 128, NDIM / 128);
    gemm_kernel<<<ggrid, 256, 0, stream>>>(xb, wb, xfb, NNODES);

    spmm_prelu_kernel<<<(NNODES + 3) / 4, 256, 0, stream>>>(xfb, adj_vals, adj_row, adj_col,
                                                            bias, prelu_a, out, NEDGES);
}

// Round 4
// 55.755 us; speedup vs baseline: 1.7765x; 1.2087x over previous
//
#include <hip/hip_runtime.h>
#include <hip/hip_bf16.h>

typedef __attribute__((ext_vector_type(4))) float f32x4;
typedef __attribute__((ext_vector_type(8))) short bf16x8;

#define NNODES 10000
#define KDIM 512
#define NDIM 512
#define NEDGES 160000

__device__ __forceinline__ unsigned short f2bf(float f) {
    __hip_bfloat16 h = __float2bfloat16(f);
    return *reinterpret_cast<unsigned short*>(&h);
}

// ---- fp32 -> bf16 conversion, 4 elems/thread ----
__global__ __launch_bounds__(256) void cvt_kernel(const float* __restrict__ src,
                                                  unsigned short* __restrict__ dst, int n) {
    int i = (blockIdx.x * 256 + threadIdx.x) * 4;
    if (i >= n) return;
    float4 v = *reinterpret_cast<const float4*>(src + i);
    ushort4 o;
    o.x = f2bf(v.x); o.y = f2bf(v.y); o.z = f2bf(v.z); o.w = f2bf(v.w);
    *reinterpret_cast<ushort4*>(dst + i) = o;
}

// ---- row_ptr: one binary search per node, done once ----
__global__ __launch_bounds__(256) void rowptr_kernel(const int* __restrict__ rows,
                                                     int* __restrict__ row_ptr, int E) {
    int i = blockIdx.x * 256 + threadIdx.x;
    if (i > NNODES) return;
    int lo = 0, hi = E;
    while (lo < hi) { int mid = (lo + hi) >> 1; if (rows[mid] < i) lo = mid + 1; else hi = mid; }
    row_ptr[i] = lo;
}

// ---- bf16 MFMA GEMM: C[M][512] = A[M][512] * B[512][512]^T, C stored as bf16 ----
__global__ __launch_bounds__(256) void gemm_kernel(const unsigned short* __restrict__ A,
                                                   const unsigned short* __restrict__ B,
                                                   unsigned short* __restrict__ C, int M) {
    __shared__ unsigned short lA[128 * 32];
    __shared__ unsigned short lB[128 * 32];
    const int tid = threadIdx.x;
    const int wid = tid >> 6;
    const int lane = tid & 63;
    const int wr = wid >> 1, wc = wid & 1;
    const int m0 = blockIdx.x * 128;
    const int n0 = blockIdx.y * 128;

    f32x4 acc[4][4] = {};

    for (int k0 = 0; k0 < KDIM; k0 += 32) {
#pragma unroll
        for (int q = 0; q < 2; q++) {
            int li = q * 256 + tid;
            int row = li >> 2, seg = li & 3;
            int grow = m0 + row; if (grow > M - 1) grow = M - 1;  // clamp OOB rows
            const unsigned short* ga = A + (size_t)grow * KDIM + k0 + seg * 8;
            __builtin_amdgcn_global_load_lds(
                (const __attribute__((address_space(1))) void*)ga,
                (__attribute__((address_space(3))) void*)(lA + (size_t)(q * 256 + wid * 64) * 8),
                16, 0, 0);
            const unsigned short* gb = B + (size_t)(n0 + row) * KDIM + k0 + seg * 8;
            __builtin_amdgcn_global_load_lds(
                (const __attribute__((address_space(1))) void*)gb,
                (__attribute__((address_space(3))) void*)(lB + (size_t)(q * 256 + wid * 64) * 8),
                16, 0, 0);
        }
        __syncthreads();

        bf16x8 af[4], bfr[4];
#pragma unroll
        for (int i = 0; i < 4; i++)
            af[i] = *reinterpret_cast<const bf16x8*>(
                lA + (size_t)(wr * 64 + i * 16 + (lane & 15)) * 32 + (lane >> 4) * 8);
#pragma unroll
        for (int j = 0; j < 4; j++)
            bfr[j] = *reinterpret_cast<const bf16x8*>(
                lB + (size_t)(wc * 64 + j * 16 + (lane & 15)) * 32 + (lane >> 4) * 8);
#pragma unroll
        for (int i = 0; i < 4; i++)
#pragma unroll
            for (int j = 0; j < 4; j++)
                acc[i][j] = __builtin_amdgcn_mfma_f32_16x16x32_bf16(af[i], bfr[j], acc[i][j], 0, 0, 0);
        __syncthreads();
    }

#pragma unroll
    for (int i = 0; i < 4; i++) {
#pragma unroll
        for (int r = 0; r < 4; r++) {
            int row = m0 + wr * 64 + i * 16 + (lane >> 4) * 4 + r;
            if (row < M) {
#pragma unroll
                for (int j = 0; j < 4; j++) {
                    int col = n0 + wc * 64 + j * 16 + (lane & 15);
                    C[(size_t)row * NDIM + col] = f2bf(acc[i][j][r]);
                }
            }
        }
    }
}

// per-edge accumulate: 8 bf16x2 words -> 8 fp32 channels
#define EDGE_ACC(vv, uu)                                   \
    a0 += (vv) * __uint_as_float((uu).x << 16);            \
    a1 += (vv) * __uint_as_float((uu).x & 0xffff0000u);    \
    a2 += (vv) * __uint_as_float((uu).y << 16);            \
    a3 += (vv) * __uint_as_float((uu).y & 0xffff0000u);    \
    a4 += (vv) * __uint_as_float((uu).z << 16);            \
    a5 += (vv) * __uint_as_float((uu).z & 0xffff0000u);    \
    a6 += (vv) * __uint_as_float((uu).w << 16);            \
    a7 += (vv) * __uint_as_float((uu).w & 0xffff0000u);

// ---- COO spmm (row_ptr precomputed) + bias + PReLU, bf16 gather ----
// 1250 blocks x 4 waves = 5000 waves, each handles exactly 2 nodes: zero tail.
__global__ __launch_bounds__(256) void spmm_prelu_kernel(
    const unsigned short* __restrict__ xb,  // [NNODES][512] bf16
    const float* __restrict__ vals,         // [E]
    const int* __restrict__ row_ptr,        // [NNODES+1]
    const int* __restrict__ cols,           // [E]
    const float* __restrict__ bias,         // [512]
    const float* __restrict__ prelu_a,      // [1]
    float* __restrict__ out) {
    const int lane = threadIdx.x & 63;
    const int gw = (blockIdx.x * 256 + threadIdx.x) >> 6;  // 0..4999

    const float4* b4 = reinterpret_cast<const float4*>(bias + lane * 8);
    const float4 b0 = b4[0], b1 = b4[1];
    const float al = prelu_a[0];

#pragma unroll
    for (int half = 0; half < 2; half++) {
        const int node = gw + half * 5000;
        const int start = __builtin_amdgcn_readfirstlane(row_ptr[node]);
        const int end = __builtin_amdgcn_readfirstlane(row_ptr[node + 1]);

        float a0 = 0.f, a1 = 0.f, a2 = 0.f, a3 = 0.f;
        float a4 = 0.f, a5 = 0.f, a6 = 0.f, a7 = 0.f;

        int e = start;
        for (; e + 3 < end; e += 4) {
            float v0 = vals[e], v1 = vals[e + 1], v2 = vals[e + 2], v3 = vals[e + 3];
            int c0 = cols[e], c1 = cols[e + 1], c2 = cols[e + 2], c3 = cols[e + 3];
            uint4 u0 = *reinterpret_cast<const uint4*>(xb + (size_t)c0 * NDIM + lane * 8);
            uint4 u1 = *reinterpret_cast<const uint4*>(xb + (size_t)c1 * NDIM + lane * 8);
            uint4 u2 = *reinterpret_cast<const uint4*>(xb + (size_t)c2 * NDIM + lane * 8);
            uint4 u3 = *reinterpret_cast<const uint4*>(xb + (size_t)c3 * NDIM + lane * 8);
            EDGE_ACC(v0, u0)
            EDGE_ACC(v1, u1)
            EDGE_ACC(v2, u2)
            EDGE_ACC(v3, u3)
        }
        for (; e < end; e++) {
            float v0 = vals[e];
            int c0 = cols[e];
            uint4 u0 = *reinterpret_cast<const uint4*>(xb + (size_t)c0 * NDIM + lane * 8);
            EDGE_ACC(v0, u0)
        }

        float o0 = a0 + b0.x, o1 = a1 + b0.y, o2 = a2 + b0.z, o3 = a3 + b0.w;
        float o4 = a4 + b1.x, o5 = a5 + b1.y, o6 = a6 + b1.z, o7 = a7 + b1.w;
        o0 = (o0 >= 0.f) ? o0 : al * o0;
        o1 = (o1 >= 0.f) ? o1 : al * o1;
        o2 = (o2 >= 0.f) ? o2 : al * o2;
        o3 = (o3 >= 0.f) ? o3 : al * o3;
        o4 = (o4 >= 0.f) ? o4 : al * o4;
        o5 = (o5 >= 0.f) ? o5 : al * o5;
        o6 = (o6 >= 0.f) ? o6 : al * o6;
        o7 = (o7 >= 0.f) ? o7 : al * o7;
        f32x4 r0; r0[0] = o0; r0[1] = o1; r0[2] = o2; r0[3] = o3;
        f32x4 r1; r1[0] = o4; r1[1] = o5; r1[2] = o6; r1[3] = o7;
        f32x4* op = reinterpret_cast<f32x4*>(out + (size_t)node * NDIM + lane * 8);
        __builtin_nontemporal_store(r0, op);
        __builtin_nontemporal_store(r1, op + 1);
    }
}

extern "C" void kernel_launch(void* const* d_in, const int* in_sizes, int n_in,
                              void* d_out, int out_size, void* d_ws, size_t ws_size,
                              hipStream_t stream) {
    const float* x        = (const float*)d_in[0];
    const float* fc_w     = (const float*)d_in[1];
    const float* bias     = (const float*)d_in[2];
    const float* prelu_a  = (const float*)d_in[3];
    const float* adj_vals = (const float*)d_in[4];
    const int*   adj_row  = (const int*)d_in[5];
    const int*   adj_col  = (const int*)d_in[6];
    float* out = (float*)d_out;

    char* ws = (char*)d_ws;
    unsigned short* xb  = (unsigned short*)ws;                        // 10,240,000 B
    unsigned short* wb  = (unsigned short*)(ws + 10240000);           //    524,288 B
    unsigned short* xfb = (unsigned short*)(ws + 10240000 + 524288);  // 10,240,000 B
    int* row_ptr        = (int*)(ws + 10240000 + 524288 + 10240000);  //     40,004 B

    const int nx = NNODES * KDIM;
    const int nw = NDIM * KDIM;
    cvt_kernel<<<(nx / 4 + 255) / 256, 256, 0, stream>>>(x, xb, nx);
    cvt_kernel<<<(nw / 4 + 255) / 256, 256, 0, stream>>>(fc_w, wb, nw);
    rowptr_kernel<<<(NNODES + 1 + 255) / 256, 256, 0, stream>>>(adj_row, row_ptr, NEDGES);

    dim3 ggrid((NNODES + 127) / 128, NDIM / 128);
    gemm_kernel<<<ggrid, 256, 0, stream>>>(xb, wb, xfb, NNODES);

    spmm_prelu_kernel<<<1250, 256, 0, stream>>>(xfb, adj_vals, row_ptr, adj_col,
                                                bias, prelu_a, out);
}

// Round 5
// 51.212 us; speedup vs baseline: 1.9341x; 1.0887x over previous
//
#include <hip/hip_runtime.h>
#include <hip/hip_bf16.h>

typedef __attribute__((ext_vector_type(4))) float f32x4;
typedef __attribute__((ext_vector_type(8))) short bf16x8;

#define NNODES 10000
#define KDIM 512
#define NDIM 512
#define NEDGES 160000

__device__ __forceinline__ unsigned short f2bf(float f) {
    __hip_bfloat16 h = __float2bfloat16(f);
    return *reinterpret_cast<unsigned short*>(&h);
}

// ---- fused prep: x->bf16 (blocks 0..4999), w->bf16 (5000..5255), row_ptr (5256..5295) ----
__global__ __launch_bounds__(256) void prep_kernel(
    const float* __restrict__ x, unsigned short* __restrict__ xb,
    const float* __restrict__ w, unsigned short* __restrict__ wb,
    const int* __restrict__ rows, int* __restrict__ row_ptr) {
    const int b = blockIdx.x;
    if (b < 5000) {
        int i = (b * 256 + threadIdx.x) * 4;
        float4 v = *reinterpret_cast<const float4*>(x + i);
        ushort4 o;
        o.x = f2bf(v.x); o.y = f2bf(v.y); o.z = f2bf(v.z); o.w = f2bf(v.w);
        *reinterpret_cast<ushort4*>(xb + i) = o;
    } else if (b < 5256) {
        int i = ((b - 5000) * 256 + threadIdx.x) * 4;
        float4 v = *reinterpret_cast<const float4*>(w + i);
        ushort4 o;
        o.x = f2bf(v.x); o.y = f2bf(v.y); o.z = f2bf(v.z); o.w = f2bf(v.w);
        *reinterpret_cast<ushort4*>(wb + i) = o;
    } else {
        int i = (b - 5256) * 256 + threadIdx.x;
        if (i <= NNODES) {
            int lo = 0, hi = NEDGES;
            while (lo < hi) { int mid = (lo + hi) >> 1; if (rows[mid] < i) lo = mid + 1; else hi = mid; }
            row_ptr[i] = lo;
        }
    }
}

// ---- bf16 MFMA GEMM: C[M][512] = A[M][512] * B[512][512]^T, C stored as bf16 ----
// BM=64, BN=128 tile, BK=32; 4 waves side by side (each wave 64x32 = 4x2 fragments).
// Grid (157, 4) = 628 blocks -> ~2.45 blocks/CU, uniform (no 2x tail round).
__global__ __launch_bounds__(256) void gemm_kernel(const unsigned short* __restrict__ A,
                                                   const unsigned short* __restrict__ B,
                                                   unsigned short* __restrict__ C, int M) {
    __shared__ unsigned short lA[64 * 32];
    __shared__ unsigned short lB[128 * 32];
    const int tid = threadIdx.x;
    const int wid = tid >> 6;
    const int lane = tid & 63;
    const int wc = wid;                     // wave col: 4 waves across BN=128
    const int m0 = blockIdx.x * 64;
    const int n0 = blockIdx.y * 128;

    f32x4 acc[4][2] = {};

    for (int k0 = 0; k0 < KDIM; k0 += 32) {
        // A tile: 64 rows x 32 bf16 = 4 KB = one 16B load/thread
        {
            int row = tid >> 2, seg = tid & 3;
            int grow = m0 + row; if (grow > M - 1) grow = M - 1;
            const unsigned short* ga = A + (size_t)grow * KDIM + k0 + seg * 8;
            __builtin_amdgcn_global_load_lds(
                (const __attribute__((address_space(1))) void*)ga,
                (__attribute__((address_space(3))) void*)(lA + (size_t)tid * 8),
                16, 0, 0);
        }
        // B tile: 128 rows x 32 bf16 = 8 KB = two 16B loads/thread
#pragma unroll
        for (int q = 0; q < 2; q++) {
            int li = q * 256 + tid;
            int row = li >> 2, seg = li & 3;
            const unsigned short* gb = B + (size_t)(n0 + row) * KDIM + k0 + seg * 8;
            __builtin_amdgcn_global_load_lds(
                (const __attribute__((address_space(1))) void*)gb,
                (__attribute__((address_space(3))) void*)(lB + (size_t)li * 8),
                16, 0, 0);
        }
        __syncthreads();

        bf16x8 af[4], bfr[2];
#pragma unroll
        for (int i = 0; i < 4; i++)
            af[i] = *reinterpret_cast<const bf16x8*>(
                lA + (size_t)(i * 16 + (lane & 15)) * 32 + (lane >> 4) * 8);
#pragma unroll
        for (int j = 0; j < 2; j++)
            bfr[j] = *reinterpret_cast<const bf16x8*>(
                lB + (size_t)(wc * 32 + j * 16 + (lane & 15)) * 32 + (lane >> 4) * 8);
#pragma unroll
        for (int i = 0; i < 4; i++)
#pragma unroll
            for (int j = 0; j < 2; j++)
                acc[i][j] = __builtin_amdgcn_mfma_f32_16x16x32_bf16(af[i], bfr[j], acc[i][j], 0, 0, 0);
        __syncthreads();
    }

#pragma unroll
    for (int i = 0; i < 4; i++) {
#pragma unroll
        for (int r = 0; r < 4; r++) {
            int row = m0 + i * 16 + (lane >> 4) * 4 + r;
            if (row < M) {
#pragma unroll
                for (int j = 0; j < 2; j++) {
                    int col = n0 + wc * 32 + j * 16 + (lane & 15);
                    C[(size_t)row * NDIM + col] = f2bf(acc[i][j][r]);
                }
            }
        }
    }
}

// per-edge accumulate into named accumulator array (indices compile-time)
#define ACC8(P, vv, uu)                                      \
    P[0] += (vv) * __uint_as_float((uu).x << 16);            \
    P[1] += (vv) * __uint_as_float((uu).x & 0xffff0000u);    \
    P[2] += (vv) * __uint_as_float((uu).y << 16);            \
    P[3] += (vv) * __uint_as_float((uu).y & 0xffff0000u);    \
    P[4] += (vv) * __uint_as_float((uu).z << 16);            \
    P[5] += (vv) * __uint_as_float((uu).z & 0xffff0000u);    \
    P[6] += (vv) * __uint_as_float((uu).w << 16);            \
    P[7] += (vv) * __uint_as_float((uu).w & 0xffff0000u);

#define GATHER(c) (*reinterpret_cast<const uint4*>(xb + (size_t)(c) * NDIM + lane * 8))

// ---- COO spmm (row_ptr precomputed) + bias + PReLU, bf16 gather ----
// 1250 blocks x 4 waves = 5000 waves; each wave owns nodes {gw, gw+5000} and
// processes BOTH edge lists concurrently (8 gathers in flight).
__global__ __launch_bounds__(256) void spmm_prelu_kernel(
    const unsigned short* __restrict__ xb,  // [NNODES][512] bf16
    const float* __restrict__ vals,         // [E]
    const int* __restrict__ row_ptr,        // [NNODES+1]
    const int* __restrict__ cols,           // [E]
    const float* __restrict__ bias,         // [512]
    const float* __restrict__ prelu_a,      // [1]
    float* __restrict__ out) {
    const int lane = threadIdx.x & 63;
    const int gw = (blockIdx.x * 256 + threadIdx.x) >> 6;  // 0..4999
    const int nd0 = gw, nd1 = gw + 5000;

    const int s0 = __builtin_amdgcn_readfirstlane(row_ptr[nd0]);
    const int e0 = __builtin_amdgcn_readfirstlane(row_ptr[nd0 + 1]);
    const int s1 = __builtin_amdgcn_readfirstlane(row_ptr[nd1]);
    const int e1 = __builtin_amdgcn_readfirstlane(row_ptr[nd1 + 1]);

    float p[8] = {}, q[8] = {};

    int i0 = s0, i1 = s1;
    // interleaved main loop: 4 edges of each node per iteration, 8 loads in flight
    while ((i0 + 4 <= e0) && (i1 + 4 <= e1)) {
        float v00 = vals[i0], v01 = vals[i0 + 1], v02 = vals[i0 + 2], v03 = vals[i0 + 3];
        int   c00 = cols[i0], c01 = cols[i0 + 1], c02 = cols[i0 + 2], c03 = cols[i0 + 3];
        float v10 = vals[i1], v11 = vals[i1 + 1], v12 = vals[i1 + 2], v13 = vals[i1 + 3];
        int   c10 = cols[i1], c11 = cols[i1 + 1], c12 = cols[i1 + 2], c13 = cols[i1 + 3];
        uint4 u00 = GATHER(c00), u01 = GATHER(c01), u02 = GATHER(c02), u03 = GATHER(c03);
        uint4 u10 = GATHER(c10), u11 = GATHER(c11), u12 = GATHER(c12), u13 = GATHER(c13);
        ACC8(p, v00, u00) ACC8(p, v01, u01) ACC8(p, v02, u02) ACC8(p, v03, u03)
        ACC8(q, v10, u10) ACC8(q, v11, u11) ACC8(q, v12, u12) ACC8(q, v13, u13)
        i0 += 4; i1 += 4;
    }
    // drain node0
    for (; i0 + 4 <= e0; i0 += 4) {
        float v0 = vals[i0], v1 = vals[i0 + 1], v2 = vals[i0 + 2], v3 = vals[i0 + 3];
        int   c0 = cols[i0], c1 = cols[i0 + 1], c2 = cols[i0 + 2], c3 = cols[i0 + 3];
        uint4 u0 = GATHER(c0), u1 = GATHER(c1), u2 = GATHER(c2), u3 = GATHER(c3);
        ACC8(p, v0, u0) ACC8(p, v1, u1) ACC8(p, v2, u2) ACC8(p, v3, u3)
    }
    for (; i0 < e0; i0++) {
        float v0 = vals[i0]; uint4 u0 = GATHER(cols[i0]);
        ACC8(p, v0, u0)
    }
    // drain node1
    for (; i1 + 4 <= e1; i1 += 4) {
        float v0 = vals[i1], v1 = vals[i1 + 1], v2 = vals[i1 + 2], v3 = vals[i1 + 3];
        int   c0 = cols[i1], c1 = cols[i1 + 1], c2 = cols[i1 + 2], c3 = cols[i1 + 3];
        uint4 u0 = GATHER(c0), u1 = GATHER(c1), u2 = GATHER(c2), u3 = GATHER(c3);
        ACC8(q, v0, u0) ACC8(q, v1, u1) ACC8(q, v2, u2) ACC8(q, v3, u3)
    }
    for (; i1 < e1; i1++) {
        float v0 = vals[i1]; uint4 u0 = GATHER(cols[i1]);
        ACC8(q, v0, u0)
    }

    const float4* b4 = reinterpret_cast<const float4*>(bias + lane * 8);
    const float4 bA = b4[0], bB = b4[1];
    const float al = prelu_a[0];

#define EPILOGUE(P, node)                                                        \
    {                                                                            \
        float o0 = P[0] + bA.x, o1 = P[1] + bA.y, o2 = P[2] + bA.z, o3 = P[3] + bA.w; \
        float o4 = P[4] + bB.x, o5 = P[5] + bB.y, o6 = P[6] + bB.z, o7 = P[7] + bB.w; \
        o0 = (o0 >= 0.f) ? o0 : al * o0;                                         \
        o1 = (o1 >= 0.f) ? o1 : al * o1;                                         \
        o2 = (o2 >= 0.f) ? o2 : al * o2;                                         \
        o3 = (o3 >= 0.f) ? o3 : al * o3;                                         \
        o4 = (o4 >= 0.f) ? o4 : al * o4;                                         \
        o5 = (o5 >= 0.f) ? o5 : al * o5;                                         \
        o6 = (o6 >= 0.f) ? o6 : al * o6;                                         \
        o7 = (o7 >= 0.f) ? o7 : al * o7;                                         \
        f32x4 r0; r0[0] = o0; r0[1] = o1; r0[2] = o2; r0[3] = o3;                \
        f32x4 r1; r1[0] = o4; r1[1] = o5; r1[2] = o6; r1[3] = o7;                \
        f32x4* op = reinterpret_cast<f32x4*>(out + (size_t)(node) * NDIM + lane * 8); \
        __builtin_nontemporal_store(r0, op);                                     \
        __builtin_nontemporal_store(r1, op + 1);                                 \
    }

    EPILOGUE(p, nd0)
    EPILOGUE(q, nd1)
}

extern "C" void kernel_launch(void* const* d_in, const int* in_sizes, int n_in,
                              void* d_out, int out_size, void* d_ws, size_t ws_size,
                              hipStream_t stream) {
    const float* x        = (const float*)d_in[0];
    const float* fc_w     = (const float*)d_in[1];
    const float* bias     = (const float*)d_in[2];
    const float* prelu_a  = (const float*)d_in[3];
    const float* adj_vals = (const float*)d_in[4];
    const int*   adj_row  = (const int*)d_in[5];
    const int*   adj_col  = (const int*)d_in[6];
    float* out = (float*)d_out;

    char* ws = (char*)d_ws;
    unsigned short* xb  = (unsigned short*)ws;                        // 10,240,000 B
    unsigned short* wb  = (unsigned short*)(ws + 10240000);           //    524,288 B
    unsigned short* xfb = (unsigned short*)(ws + 10240000 + 524288);  // 10,240,000 B
    int* row_ptr        = (int*)(ws + 10240000 + 524288 + 10240000);  //     40,004 B

    prep_kernel<<<5296, 256, 0, stream>>>(x, xb, fc_w, wb, adj_row, row_ptr);

    dim3 ggrid((NNODES + 63) / 64, NDIM / 128);
    gemm_kernel<<<ggrid, 256, 0, stream>>>(xb, wb, xfb, NNODES);

    spmm_prelu_kernel<<<1250, 256, 0, stream>>>(xfb, adj_vals, row_ptr, adj_col,
                                                bias, prelu_a, out);
}